// Round 4
// baseline (490.460 us; speedup 1.0000x reference)
//
#include <hip/hip_runtime.h>
#include <hip/hip_bf16.h>
#include <math.h>

// Problem constants
#define B_  2
#define K_  512
#define SD_ 60
#define NA_ 5
#define E_  256
#define H_  4
#define D_  64
#define FF_ 1024
#define NL_ 2
#define L_  (3 * K_)          // 1536 tokens per batch
#define M_  (B_ * L_)         // 3072 rows total
#define EPS_F 1e-6f
#define LN_EPS 1e-5f
#define CHK 64                // attention chunk size
#define NC_ (L_ / CHK)        // 24 chunks per (b,h)

using bf16x8 = __attribute__((ext_vector_type(8))) short;
using f32x4  = __attribute__((ext_vector_type(4))) float;
typedef unsigned short u16;

__device__ inline u16 f2b(float v) {
    __hip_bfloat16 h = __float2bfloat16(v);
    return *(u16*)&h;
}
__device__ inline float b2f(u16 v) {
    __hip_bfloat16 h = *(__hip_bfloat16*)&v;
    return __bfloat162float(h);
}

// ---------------------------------------------------------------------------
// Weight convert + transpose: W[K][N] fp32 -> Wt[N][K] bf16, 32x32 tiles
// ---------------------------------------------------------------------------
__global__ __launch_bounds__(256) void wconv_kernel(
    const float* __restrict__ qkv_w, const float* __restrict__ out_w,
    const float* __restrict__ ffn1_w, const float* __restrict__ ffn2_w,
    u16* __restrict__ qkvT, u16* __restrict__ outT,
    u16* __restrict__ f1T, u16* __restrict__ f2T)
{
    int tb = blockIdx.x;
    int layer = tb / 768;
    int r = tb % 768;
    const float* src; u16* dst; int K, N, tidx;
    if (r < 192)      { src = qkv_w  + layer * 196608; dst = qkvT + layer * 196608; K = 256;  N = 768;  tidx = r; }
    else if (r < 256) { src = out_w  + layer * 65536;  dst = outT + layer * 65536;  K = 256;  N = 256;  tidx = r - 192; }
    else if (r < 512) { src = ffn1_w + layer * 262144; dst = f1T  + layer * 262144; K = 256;  N = 1024; tidx = r - 256; }
    else              { src = ffn2_w + layer * 262144; dst = f2T  + layer * 262144; K = 1024; N = 256;  tidx = r - 512; }
    int tilesN = N >> 5;
    int k0 = (tidx / tilesN) << 5;
    int n0 = (tidx % tilesN) << 5;
    __shared__ u16 T[32][33];
    int c = threadIdx.x & 31, r0 = threadIdx.x >> 5;
    for (int rr = r0; rr < 32; rr += 8)
        T[rr][c] = f2b(src[(size_t)(k0 + rr) * N + n0 + c]);
    __syncthreads();
    for (int rr = r0; rr < 32; rr += 8)
        dst[(size_t)(n0 + rr) * K + k0 + c] = T[c][rr];
}

// ---------------------------------------------------------------------------
// Embed + interleave + LN1(layer0), one wave per token
// writes X (fp32 residual) and Y (bf16 normalized)
// ---------------------------------------------------------------------------
__global__ __launch_bounds__(256) void embed_ln_kernel(
    const float* __restrict__ rtg, const float* __restrict__ state,
    const float* __restrict__ action,
    const float* __restrict__ rtg_w, const float* __restrict__ rtg_b,
    const float* __restrict__ state_w, const float* __restrict__ state_b,
    const float* __restrict__ action_w, const float* __restrict__ action_b,
    const float* __restrict__ pos,
    const float* __restrict__ g, const float* __restrict__ bta,
    float* __restrict__ X, u16* __restrict__ Y)
{
    int tok = blockIdx.x * 4 + (threadIdx.x >> 6);
    int lane = threadIdx.x & 63;
    int b = tok / L_, l = tok % L_;
    int j = l % 3, t = l / 3;
    int e0 = lane * 4;
    float4 val = *(const float4*)(pos + t * E_ + e0);
    if (j == 0) {
        float rv = rtg[b * K_ + t];
        float4 w = *(const float4*)(rtg_w + e0);
        float4 bb = *(const float4*)(rtg_b + e0);
        val.x += rv * w.x + bb.x; val.y += rv * w.y + bb.y;
        val.z += rv * w.z + bb.z; val.w += rv * w.w + bb.w;
    } else if (j == 1) {
        float4 a = *(const float4*)(state_b + e0);
        const float* srow = state + ((size_t)b * K_ + t) * SD_;
        for (int i = 0; i < SD_; i++) {
            float s = srow[i];
            float4 w = *(const float4*)(state_w + (size_t)i * E_ + e0);
            a.x += s * w.x; a.y += s * w.y; a.z += s * w.z; a.w += s * w.w;
        }
        val.x += a.x; val.y += a.y; val.z += a.z; val.w += a.w;
    } else {
        float4 a = *(const float4*)(action_b + e0);
        const float* arow = action + ((size_t)b * K_ + t) * NA_;
        #pragma unroll
        for (int i = 0; i < NA_; i++) {
            float s = arow[i];
            float4 w = *(const float4*)(action_w + (size_t)i * E_ + e0);
            a.x += s * w.x; a.y += s * w.y; a.z += s * w.z; a.w += s * w.w;
        }
        val.x += a.x; val.y += a.y; val.z += a.z; val.w += a.w;
    }
    *(float4*)(X + (size_t)tok * E_ + e0) = val;
    float s = val.x + val.y + val.z + val.w;
    #pragma unroll
    for (int o = 32; o; o >>= 1) s += __shfl_xor(s, o, 64);
    float mean = s * (1.f / E_);
    float dx = val.x - mean, dy = val.y - mean, dz = val.z - mean, dw = val.w - mean;
    float q = dx * dx + dy * dy + dz * dz + dw * dw;
    #pragma unroll
    for (int o = 32; o; o >>= 1) q += __shfl_xor(q, o, 64);
    float inv = rsqrtf(q * (1.f / E_) + LN_EPS);
    float4 gv = *(const float4*)(g + e0);
    float4 bv = *(const float4*)(bta + e0);
    ushort4 u;
    u.x = f2b(dx * inv * gv.x + bv.x); u.y = f2b(dy * inv * gv.y + bv.y);
    u.z = f2b(dz * inv * gv.z + bv.z); u.w = f2b(dw * inv * gv.w + bv.w);
    *(ushort4*)(Y + (size_t)tok * E_ + e0) = u;
}

// ---------------------------------------------------------------------------
// MFMA bf16 GEMM: C[M,N] = epi(A[M,K]bf16 @ Bt[N,K]bf16^T + bias)
// 128x128 tile, 256 threads = 4 waves (2x2 of 64x64), BK=32
// EPI: 0 none, 1 exact gelu. Output bf16.
// ---------------------------------------------------------------------------
template <int EPI>
__global__ __launch_bounds__(256) void mgemm(
    const u16* __restrict__ A, const u16* __restrict__ Bt,
    const float* __restrict__ bias,
    u16* __restrict__ C, int M, int N, int Kd)
{
    __shared__ __align__(16) u16 As[128 * 40];
    __shared__ __align__(16) u16 Bs[128 * 40];
    int tid = threadIdx.x;
    int bm = blockIdx.y * 128, bn = blockIdx.x * 128;
    int wave = tid >> 6, lane = tid & 63;
    int wm = (wave >> 1) * 64, wn = (wave & 1) * 64;
    int lr = lane & 15, kg = lane >> 4;

    int s0 = tid, s1 = tid + 256;
    int r0 = s0 >> 2, g0 = (s0 & 3) * 8;
    int r1 = s1 >> 2, g1 = (s1 & 3) * 8;

    f32x4 acc[4][4] = {};

    for (int k0 = 0; k0 < Kd; k0 += 32) {
        uint4 a0 = *(const uint4*)(A + (size_t)(bm + r0) * Kd + k0 + g0);
        uint4 a1 = *(const uint4*)(A + (size_t)(bm + r1) * Kd + k0 + g1);
        uint4 b0 = *(const uint4*)(Bt + (size_t)(bn + r0) * Kd + k0 + g0);
        uint4 b1 = *(const uint4*)(Bt + (size_t)(bn + r1) * Kd + k0 + g1);
        __syncthreads();
        *(uint4*)&As[r0 * 40 + g0] = a0;
        *(uint4*)&As[r1 * 40 + g1] = a1;
        *(uint4*)&Bs[r0 * 40 + g0] = b0;
        *(uint4*)&Bs[r1 * 40 + g1] = b1;
        __syncthreads();
        bf16x8 af[4], bg[4];
        #pragma unroll
        for (int i = 0; i < 4; i++)
            af[i] = *(const bf16x8*)&As[(wm + i * 16 + lr) * 40 + kg * 8];
        #pragma unroll
        for (int j = 0; j < 4; j++)
            bg[j] = *(const bf16x8*)&Bs[(wn + j * 16 + lr) * 40 + kg * 8];
        #pragma unroll
        for (int i = 0; i < 4; i++)
            #pragma unroll
            for (int j = 0; j < 4; j++)
                acc[i][j] = __builtin_amdgcn_mfma_f32_16x16x32_bf16(
                    af[i], bg[j], acc[i][j], 0, 0, 0);
    }

    int crow = (lane >> 4) * 4;
    int ccol = lane & 15;
    #pragma unroll
    for (int i = 0; i < 4; i++) {
        #pragma unroll
        for (int j = 0; j < 4; j++) {
            int col = bn + wn + j * 16 + ccol;
            float bc = bias[col];
            #pragma unroll
            for (int r = 0; r < 4; r++) {
                int row = bm + wm + i * 16 + crow + r;
                float v = acc[i][j][r] + bc;
                if (EPI == 1) v = 0.5f * v * (1.0f + erff(v * 0.70710678118654752f));
                C[(size_t)row * N + col] = f2b(v);
            }
        }
    }
}

// ---------------------------------------------------------------------------
// MFMA GEMM + residual + fused LayerNorm. N = 256 (full row per block).
// BM=128, BN=256, 256 threads = 4 waves as 2x2 of 64x128.
// Writes X (fp32 residual out) and Y (bf16 LN output).
// ---------------------------------------------------------------------------
__global__ __launch_bounds__(256, 1) void mgemm_ln(
    const u16* __restrict__ A, const u16* __restrict__ Bt,
    const float* __restrict__ bias,
    const float* __restrict__ g, const float* __restrict__ bta,
    float* __restrict__ X, u16* __restrict__ Y, int Kd)
{
    __shared__ __align__(16) u16 As[128 * 40];
    __shared__ __align__(16) u16 Bs[256 * 40];
    __shared__ float sbias[256], sg[256], sb[256];
    __shared__ float redS[128][2], redQ[128][2];
    __shared__ float meanL[128], invL[128];
    int tid = threadIdx.x;
    int bm = blockIdx.x * 128;
    int wave = tid >> 6, lane = tid & 63;
    int wm = (wave >> 1) * 64;
    int wn = (wave & 1) * 128;
    int half = wave & 1;
    int lr = lane & 15, kg = lane >> 4;

    sbias[tid] = bias[tid];
    sg[tid] = g[tid];
    sb[tid] = bta[tid];

    int r0 = tid >> 2, gA = (tid & 3) * 8;   // A: 512 segs, 2/thread
    int r1 = (tid + 256) >> 2;

    f32x4 acc[4][8] = {};

    for (int k0 = 0; k0 < Kd; k0 += 32) {
        uint4 a0 = *(const uint4*)(A + (size_t)(bm + r0) * Kd + k0 + gA);
        uint4 a1 = *(const uint4*)(A + (size_t)(bm + r1) * Kd + k0 + gA);
        uint4 bv[4];
        #pragma unroll
        for (int s = 0; s < 4; s++) {
            int seg = tid + 256 * s;
            int rr = seg >> 2, gg = (seg & 3) * 8;
            bv[s] = *(const uint4*)(Bt + (size_t)rr * Kd + k0 + gg);
        }
        __syncthreads();
        *(uint4*)&As[r0 * 40 + gA] = a0;
        *(uint4*)&As[r1 * 40 + gA] = a1;
        #pragma unroll
        for (int s = 0; s < 4; s++) {
            int seg = tid + 256 * s;
            int rr = seg >> 2, gg = (seg & 3) * 8;
            *(uint4*)&Bs[rr * 40 + gg] = bv[s];
        }
        __syncthreads();
        bf16x8 af[4], bg[8];
        #pragma unroll
        for (int i = 0; i < 4; i++)
            af[i] = *(const bf16x8*)&As[(wm + i * 16 + lr) * 40 + kg * 8];
        #pragma unroll
        for (int j = 0; j < 8; j++)
            bg[j] = *(const bf16x8*)&Bs[(wn + j * 16 + lr) * 40 + kg * 8];
        #pragma unroll
        for (int i = 0; i < 4; i++)
            #pragma unroll
            for (int j = 0; j < 8; j++)
                acc[i][j] = __builtin_amdgcn_mfma_f32_16x16x32_bf16(
                    af[i], bg[j], acc[i][j], 0, 0, 0);
    }

    // pass 1: v = acc + bias + Res; accumulate row partial sums
    #pragma unroll
    for (int i = 0; i < 4; i++) {
        #pragma unroll
        for (int r = 0; r < 4; r++) {
            int row = wm + i * 16 + kg * 4 + r;
            float s = 0.f, sq = 0.f;
            #pragma unroll
            for (int j = 0; j < 8; j++) {
                int col = wn + j * 16 + lr;
                float v = acc[i][j][r] + sbias[col]
                        + X[(size_t)(bm + row) * 256 + col];
                acc[i][j][r] = v;
                s += v; sq += v * v;
            }
            #pragma unroll
            for (int o = 1; o < 16; o <<= 1) {
                s += __shfl_xor(s, o, 64);
                sq += __shfl_xor(sq, o, 64);
            }
            if (lr == 0) { redS[row][half] = s; redQ[row][half] = sq; }
        }
    }
    __syncthreads();
    if (tid < 128) {
        float s = redS[tid][0] + redS[tid][1];
        float sq = redQ[tid][0] + redQ[tid][1];
        float mean = s * (1.f / 256.f);
        float var = sq * (1.f / 256.f) - mean * mean;
        meanL[tid] = mean;
        invL[tid] = rsqrtf(var + LN_EPS);
    }
    __syncthreads();

    // pass 2: write residual X and normalized Y
    #pragma unroll
    for (int i = 0; i < 4; i++) {
        #pragma unroll
        for (int r = 0; r < 4; r++) {
            int row = wm + i * 16 + kg * 4 + r;
            float mean = meanL[row], inv = invL[row];
            #pragma unroll
            for (int j = 0; j < 8; j++) {
                int col = wn + j * 16 + lr;
                float v = acc[i][j][r];
                X[(size_t)(bm + row) * 256 + col] = v;
                Y[(size_t)(bm + row) * 256 + col] =
                    f2b((v - mean) * inv * sg[col] + sb[col]);
            }
        }
    }
}

// ---------------------------------------------------------------------------
// Chunked linear attention; qkv bf16: (B,L,768) q|k|v head-major D=64
// Pass A (MFMA): per-chunk S[d][e] = sum_t k[t][d] v[t][e], z[d] = sum_t k[t][d]
// ---------------------------------------------------------------------------
__global__ __launch_bounds__(256) void chunk_sum_kernel(
    const u16* __restrict__ QKV, float* __restrict__ S, float* __restrict__ Z)
{
    int blk = blockIdx.x;                  // (b*H+h)*NC + c
    int c = blk % NC_;
    int bh = blk / NC_;
    int h = bh % H_;
    int b = bh / H_;
    __shared__ __align__(16) u16 Kt[64 * 72];   // [d][t]
    __shared__ __align__(16) u16 Vt[64 * 72];   // [e][t]
    int tid = threadIdx.x;
    const size_t base = ((size_t)b * L_ + (size_t)c * CHK) * 768 + h * 64;
    for (int i = tid; i < 1024; i += 256) {
        int t = i >> 4, d4 = (i & 15) << 2;
        ushort4 k = *(const ushort4*)(QKV + base + (size_t)t * 768 + 256 + d4);
        ushort4 v = *(const ushort4*)(QKV + base + (size_t)t * 768 + 512 + d4);
        Kt[(d4 + 0) * 72 + t] = f2b(fmaxf(b2f(k.x), 0.f) + EPS_F);
        Kt[(d4 + 1) * 72 + t] = f2b(fmaxf(b2f(k.y), 0.f) + EPS_F);
        Kt[(d4 + 2) * 72 + t] = f2b(fmaxf(b2f(k.z), 0.f) + EPS_F);
        Kt[(d4 + 3) * 72 + t] = f2b(fmaxf(b2f(k.w), 0.f) + EPS_F);
        Vt[(d4 + 0) * 72 + t] = v.x;
        Vt[(d4 + 1) * 72 + t] = v.y;
        Vt[(d4 + 2) * 72 + t] = v.z;
        Vt[(d4 + 3) * 72 + t] = v.w;
    }
    __syncthreads();
    int wave = tid >> 6, lane = tid & 63;
    int lr = lane & 15, kg = lane >> 4;
    int wm = wave * 16;
    bf16x8 a0 = *(const bf16x8*)&Kt[(wm + lr) * 72 + kg * 8];
    bf16x8 a1 = *(const bf16x8*)&Kt[(wm + lr) * 72 + 32 + kg * 8];
    f32x4 acc[4] = {};
    #pragma unroll
    for (int j = 0; j < 4; j++) {
        bf16x8 b0 = *(const bf16x8*)&Vt[(j * 16 + lr) * 72 + kg * 8];
        bf16x8 b1 = *(const bf16x8*)&Vt[(j * 16 + lr) * 72 + 32 + kg * 8];
        acc[j] = __builtin_amdgcn_mfma_f32_16x16x32_bf16(a0, b0, acc[j], 0, 0, 0);
        acc[j] = __builtin_amdgcn_mfma_f32_16x16x32_bf16(a1, b1, acc[j], 0, 0, 0);
    }
    if (tid < 64) {
        float z = 0.f;
        #pragma unroll 8
        for (int t = 0; t < 64; t++) z += b2f(Kt[tid * 72 + t]);
        Z[(size_t)blk * 64 + tid] = z;
    }
    float* Sp = S + (size_t)blk * 4096;
    #pragma unroll
    for (int j = 0; j < 4; j++) {
        #pragma unroll
        for (int r = 0; r < 4; r++) {
            int d = wm + kg * 4 + r;
            int e = j * 16 + lr;
            Sp[d * 64 + e] = acc[j][r];
        }
    }
}

// ---------------------------------------------------------------------------
// Pass B (MFMA, fused exclusive prefix):
// o = (Q@KVstate + tril(Q@K^T)@V) / max(Q.kz + rowsum, 1e-6)
// KVstate/kz computed in-block by summing per-chunk S/Z of chunks < c.
// ---------------------------------------------------------------------------
__global__ __launch_bounds__(256) void chunk_out_kernel(
    const u16* __restrict__ QKV, const float* __restrict__ S,
    const float* __restrict__ Z, u16* __restrict__ O)
{
    int blk = blockIdx.x;
    int c = blk % NC_;
    int bh = blk / NC_;
    int h = bh % H_;
    int b = bh / H_;
    __shared__ __align__(16) u16 Qb[64 * 72];    // [t][d]
    __shared__ __align__(16) u16 Kb[64 * 72];    // [t][d]
    __shared__ __align__(16) u16 Vt[64 * 72];    // [e][t]
    __shared__ __align__(16) u16 KVt[64 * 72];   // [e][d]
    __shared__ __align__(16) u16 Ps[64 * 72];    // [t][s] masked scores
    __shared__ float kzs[64];
    __shared__ float rows[64];
    __shared__ float invs[64];
    int tid = threadIdx.x;
    const size_t base = ((size_t)b * L_ + (size_t)c * CHK) * 768 + h * 64;
    const float* Sbh = S + (size_t)bh * NC_ * 4096;
    for (int i = tid; i < 1024; i += 256) {
        int t = i >> 4, d4 = (i & 15) << 2;
        ushort4 q = *(const ushort4*)(QKV + base + (size_t)t * 768 + d4);
        ushort4 k = *(const ushort4*)(QKV + base + (size_t)t * 768 + 256 + d4);
        ushort4 v = *(const ushort4*)(QKV + base + (size_t)t * 768 + 512 + d4);
        ushort4 qu, ku;
        qu.x = f2b(fmaxf(b2f(q.x), 0.f) + EPS_F); qu.y = f2b(fmaxf(b2f(q.y), 0.f) + EPS_F);
        qu.z = f2b(fmaxf(b2f(q.z), 0.f) + EPS_F); qu.w = f2b(fmaxf(b2f(q.w), 0.f) + EPS_F);
        ku.x = f2b(fmaxf(b2f(k.x), 0.f) + EPS_F); ku.y = f2b(fmaxf(b2f(k.y), 0.f) + EPS_F);
        ku.z = f2b(fmaxf(b2f(k.z), 0.f) + EPS_F); ku.w = f2b(fmaxf(b2f(k.w), 0.f) + EPS_F);
        *(ushort4*)&Qb[t * 72 + d4] = qu;
        *(ushort4*)&Kb[t * 72 + d4] = ku;
        Vt[(d4 + 0) * 72 + t] = v.x;
        Vt[(d4 + 1) * 72 + t] = v.y;
        Vt[(d4 + 2) * 72 + t] = v.z;
        Vt[(d4 + 3) * 72 + t] = v.w;
        // exclusive prefix of chunk states: KV[d][e4..] = sum_{cc<c} S_cc
        int d = t, e4 = d4;
        float4 a = make_float4(0.f, 0.f, 0.f, 0.f);
        for (int cc = 0; cc < c; cc++) {
            float4 s4 = *(const float4*)(Sbh + (size_t)cc * 4096 + d * 64 + e4);
            a.x += s4.x; a.y += s4.y; a.z += s4.z; a.w += s4.w;
        }
        KVt[(e4 + 0) * 72 + d] = f2b(a.x);
        KVt[(e4 + 1) * 72 + d] = f2b(a.y);
        KVt[(e4 + 2) * 72 + d] = f2b(a.z);
        KVt[(e4 + 3) * 72 + d] = f2b(a.w);
    }
    if (tid < 64) {
        float z = 0.f;
        const float* Zbh = Z + (size_t)bh * NC_ * 64;
        for (int cc = 0; cc < c; cc++) z += Zbh[cc * 64 + tid];
        kzs[tid] = z;
    }
    __syncthreads();

    int wave = tid >> 6, lane = tid & 63;
    int lr = lane & 15, kg = lane >> 4;
    int wm = wave * 16;

    bf16x8 aq0 = *(const bf16x8*)&Qb[(wm + lr) * 72 + kg * 8];
    bf16x8 aq1 = *(const bf16x8*)&Qb[(wm + lr) * 72 + 32 + kg * 8];

    // S_qk = Q @ K^T  (rows wm.., all 64 cols)
    f32x4 accs[4] = {};
    #pragma unroll
    for (int j = 0; j < 4; j++) {
        bf16x8 b0 = *(const bf16x8*)&Kb[(j * 16 + lr) * 72 + kg * 8];
        bf16x8 b1 = *(const bf16x8*)&Kb[(j * 16 + lr) * 72 + 32 + kg * 8];
        accs[j] = __builtin_amdgcn_mfma_f32_16x16x32_bf16(aq0, b0, accs[j], 0, 0, 0);
        accs[j] = __builtin_amdgcn_mfma_f32_16x16x32_bf16(aq1, b1, accs[j], 0, 0, 0);
    }
    // mask tril, accumulate row sums, write P to LDS
    float rsum[4] = {0.f, 0.f, 0.f, 0.f};
    #pragma unroll
    for (int j = 0; j < 4; j++) {
        #pragma unroll
        for (int r = 0; r < 4; r++) {
            int m = wm + kg * 4 + r;
            int n = j * 16 + lr;
            float v = (n <= m) ? accs[j][r] : 0.f;
            rsum[r] += v;
            Ps[m * 72 + n] = f2b(v);
        }
    }
    #pragma unroll
    for (int r = 0; r < 4; r++) {
        float s = rsum[r];
        s += __shfl_xor(s, 1, 64);
        s += __shfl_xor(s, 2, 64);
        s += __shfl_xor(s, 4, 64);
        s += __shfl_xor(s, 8, 64);
        if (lr == 0) rows[wm + kg * 4 + r] = s;
    }
    __syncthreads();

    if (tid < 64) {
        float den = rows[tid];
        float acc = 0.f;
        #pragma unroll 8
        for (int d = 0; d < 64; d++) acc += b2f(Qb[tid * 72 + d]) * kzs[d];
        invs[tid] = 1.f / fmaxf(den + acc, 1e-6f);
    }

    bf16x8 ap0 = *(const bf16x8*)&Ps[(wm + lr) * 72 + kg * 8];
    bf16x8 ap1 = *(const bf16x8*)&Ps[(wm + lr) * 72 + 32 + kg * 8];
    f32x4 accn[4] = {};
    #pragma unroll
    for (int j = 0; j < 4; j++) {
        bf16x8 b0 = *(const bf16x8*)&KVt[(j * 16 + lr) * 72 + kg * 8];
        bf16x8 b1 = *(const bf16x8*)&KVt[(j * 16 + lr) * 72 + 32 + kg * 8];
        accn[j] = __builtin_amdgcn_mfma_f32_16x16x32_bf16(aq0, b0, accn[j], 0, 0, 0);
        accn[j] = __builtin_amdgcn_mfma_f32_16x16x32_bf16(aq1, b1, accn[j], 0, 0, 0);
        bf16x8 c0 = *(const bf16x8*)&Vt[(j * 16 + lr) * 72 + kg * 8];
        bf16x8 c1 = *(const bf16x8*)&Vt[(j * 16 + lr) * 72 + 32 + kg * 8];
        accn[j] = __builtin_amdgcn_mfma_f32_16x16x32_bf16(ap0, c0, accn[j], 0, 0, 0);
        accn[j] = __builtin_amdgcn_mfma_f32_16x16x32_bf16(ap1, c1, accn[j], 0, 0, 0);
    }
    __syncthreads();

    u16* Op = O + ((size_t)b * L_ + (size_t)c * CHK) * E_ + h * 64;
    #pragma unroll
    for (int j = 0; j < 4; j++) {
        #pragma unroll
        for (int r = 0; r < 4; r++) {
            int m = wm + kg * 4 + r;
            int e = j * 16 + lr;
            Op[(size_t)m * E_ + e] = f2b(accn[j][r] * invs[m]);
        }
    }
}

// ---------------------------------------------------------------------------
// Prediction head: out[b,t,na] = y[b, 3t+1, :] . pred_w[:,na] + pred_b[na]
// ---------------------------------------------------------------------------
__global__ __launch_bounds__(256) void pred_kernel(
    const u16* __restrict__ Y, const float* __restrict__ W,
    const float* __restrict__ bias, float* __restrict__ Out)
{
    int idx = blockIdx.x * 256 + threadIdx.x;
    if (idx >= B_ * K_ * NA_) return;
    int na = idx % NA_;
    int t = (idx / NA_) % K_;
    int b = idx / (NA_ * K_);
    const u16* y = Y + ((size_t)b * L_ + 3 * t + 1) * E_;
    float acc = bias[na];
    #pragma unroll 8
    for (int e = 0; e < E_; e++) acc += b2f(y[e]) * W[e * NA_ + na];
    Out[idx] = acc;
}

// ---------------------------------------------------------------------------
extern "C" void kernel_launch(void* const* d_in, const int* in_sizes, int n_in,
                              void* d_out, int out_size, void* d_ws, size_t ws_size,
                              hipStream_t stream) {
    const float* rtg      = (const float*)d_in[0];
    const float* state    = (const float*)d_in[1];
    const float* action   = (const float*)d_in[2];
    const float* rtg_w    = (const float*)d_in[3];
    const float* rtg_b    = (const float*)d_in[4];
    const float* state_w  = (const float*)d_in[5];
    const float* state_b  = (const float*)d_in[6];
    const float* action_w = (const float*)d_in[7];
    const float* action_b = (const float*)d_in[8];
    const float* pos_emb  = (const float*)d_in[9];
    const float* norm1_g  = (const float*)d_in[10];
    const float* norm1_b  = (const float*)d_in[11];
    const float* qkv_w    = (const float*)d_in[12];
    const float* qkv_b    = (const float*)d_in[13];
    const float* out_w    = (const float*)d_in[14];
    const float* out_b    = (const float*)d_in[15];
    const float* norm2_g  = (const float*)d_in[16];
    const float* norm2_b  = (const float*)d_in[17];
    const float* ffn1_w   = (const float*)d_in[18];
    const float* ffn1_b   = (const float*)d_in[19];
    const float* ffn2_w   = (const float*)d_in[20];
    const float* ffn2_b   = (const float*)d_in[21];
    const float* normf_g  = (const float*)d_in[22];
    const float* normf_b  = (const float*)d_in[23];
    const float* pred_w   = (const float*)d_in[24];
    const float* pred_b   = (const float*)d_in[25];
    float* out = (float*)d_out;

    // workspace layout
    float* ws = (float*)d_ws;
    float* x    = ws;                        // 786432 f
    float* S    = x + 786432;                // 786432 f
    float* Z    = S + 786432;                // 12288 f
    u16*   yb   = (u16*)(Z + 12288);         // 786432 u16
    u16*   qkvb = yb + 786432;               // 2359296 u16
    u16*   att  = qkvb + 2359296;            // 786432
    u16*   h1   = att + 786432;              // 3145728
    u16*   qkvT = h1 + 3145728;              // 393216
    u16*   outT = qkvT + 393216;             // 131072
    u16*   f1T  = outT + 131072;             // 524288
    u16*   f2T  = f1T + 524288;              // 524288

    wconv_kernel<<<1536, 256, 0, stream>>>(qkv_w, out_w, ffn1_w, ffn2_w,
                                           qkvT, outT, f1T, f2T);
    embed_ln_kernel<<<M_ / 4, 256, 0, stream>>>(
        rtg, state, action, rtg_w, rtg_b, state_w, state_b,
        action_w, action_b, pos_emb, norm1_g, norm1_b, x, yb);

    for (int i = 0; i < NL_; i++) {
        mgemm<0><<<dim3(768 / 128, M_ / 128), 256, 0, stream>>>(
            yb, qkvT + (size_t)i * 196608, qkv_b + i * 768, qkvb,
            M_, 768, E_);
        chunk_sum_kernel<<<B_ * H_ * NC_, 256, 0, stream>>>(qkvb, S, Z);
        chunk_out_kernel<<<B_ * H_ * NC_, 256, 0, stream>>>(qkvb, S, Z, att);
        // out-proj + residual + LN2 fused
        mgemm_ln<<<M_ / 128, 256, 0, stream>>>(
            att, outT + (size_t)i * 65536, out_b + i * E_,
            norm2_g + i * E_, norm2_b + i * E_, x, yb, E_);
        // FFN1 + gelu
        mgemm<1><<<dim3(FF_ / 128, M_ / 128), 256, 0, stream>>>(
            yb, f1T + (size_t)i * 262144, ffn1_b + i * FF_, h1,
            M_, FF_, E_);
        // FFN2 + residual + (next LN1 or final LN) fused
        const float* gnext = (i == 0) ? (norm1_g + E_) : normf_g;
        const float* bnext = (i == 0) ? (norm1_b + E_) : normf_b;
        mgemm_ln<<<M_ / 128, 256, 0, stream>>>(
            h1, f2T + (size_t)i * 262144, ffn2_b + i * E_,
            gnext, bnext, x, yb, FF_);
    }
    pred_kernel<<<(B_ * K_ * NA_ + 255) / 256, 256, 0, stream>>>(
        yb, pred_w, pred_b, out);
}